// Round 1
// baseline (381.115 us; speedup 1.0000x reference)
//
#include <hip/hip_runtime.h>

// Morphological opening: dilate3x3(erode3x3(x)), flat SE, SAME padding.
// Erosion pads with +inf (OOB inputs are identity for min);
// dilation pads with -inf (erosion values at OOB positions excluded from max).
// Fused single-pass kernel: 5x5 input dependency per output pixel, staged in LDS
// with separable min/max passes.

#define IMG_H 1024
#define IMG_W 1024
#define TX 128          // output tile width
#define TY 16           // output tile height
#define IN_W (TX + 8)   // 136: cols ox-4 .. ox+TX+3 (float4-aligned halo)
#define IN_H (TY + 4)   // 20:  rows oy-2 .. oy+TY+1
#define ER_W (TX + 2)   // 130: erosion cols ox-1 .. ox+TX
#define ER_H (TY + 2)   // 18:  erosion rows oy-1 .. oy+TY
#define NT 256

__global__ __launch_bounds__(NT)
void open3x3_fused(const float* __restrict__ in, float* __restrict__ out) {
    __shared__ float s_in[IN_H][IN_W];  // input tile, +inf outside image
    __shared__ float s_h [IN_H][ER_W];  // horizontal 3-min
    __shared__ float s_e [ER_H][ER_W];  // erosion, -inf at OOB positions
    __shared__ float s_m [ER_H][TX];    // horizontal 3-max of erosion

    const int t  = threadIdx.x;
    const int ox = blockIdx.x * TX;
    const int oy = blockIdx.y * TY;
    const int img_elems = IMG_H * IMG_W;
    const float* img  = in  + (size_t)blockIdx.z * img_elems;
    float*       outp = out + (size_t)blockIdx.z * img_elems;

    const float PINF = __builtin_inff();
    const float NINF = -__builtin_inff();

    // ---- Stage 1: global -> LDS input tile (vectorized, +inf OOB) ----
    // IN_H * IN_W/4 = 20 * 34 = 680 float4 slots
    for (int idx = t; idx < IN_H * (IN_W / 4); idx += NT) {
        int row = idx / (IN_W / 4);
        int c4  = idx % (IN_W / 4);
        int r = oy - 2 + row;
        int c = ox - 4 + 4 * c4;
        float4 v;
        if (r >= 0 && r < IMG_H && c >= 0 && c + 3 < IMG_W) {
            v = *(const float4*)(img + r * IMG_W + c);
        } else {
            const float* rowp = img + r * IMG_W;
            bool rin = (r >= 0 && r < IMG_H);
            v.x = (rin && c + 0 >= 0 && c + 0 < IMG_W) ? rowp[c + 0] : PINF;
            v.y = (rin && c + 1 >= 0 && c + 1 < IMG_W) ? rowp[c + 1] : PINF;
            v.z = (rin && c + 2 >= 0 && c + 2 < IMG_W) ? rowp[c + 2] : PINF;
            v.w = (rin && c + 3 >= 0 && c + 3 < IMG_W) ? rowp[c + 3] : PINF;
        }
        *(float4*)&s_in[row][4 * c4] = v;
    }
    __syncthreads();

    // ---- Stage 2: horizontal 3-min ----
    // s_h[y][x] = min over input cols (ox-1+x-1 .. ox-1+x+1); smem col sx = x+3
    for (int idx = t; idx < IN_H * ER_W; idx += NT) {
        int y = idx / ER_W;
        int x = idx % ER_W;
        int sx = x + 3;
        float a = s_in[y][sx - 1];
        float b = s_in[y][sx];
        float c = s_in[y][sx + 1];
        s_h[y][x] = fminf(fminf(a, b), c);
    }
    __syncthreads();

    // ---- Stage 3: vertical 3-min => erosion; mask OOB positions to -inf ----
    for (int idx = t; idx < ER_H * ER_W; idx += NT) {
        int y = idx / ER_W;
        int x = idx % ER_W;
        int r = oy - 1 + y;
        int c = ox - 1 + x;
        float v;
        if (r < 0 || r >= IMG_H || c < 0 || c >= IMG_W) {
            v = NINF;  // erosion at out-of-image position: excluded from dilation max
        } else {
            v = fminf(fminf(s_h[y][x], s_h[y + 1][x]), s_h[y + 2][x]);
        }
        s_e[y][x] = v;
    }
    __syncthreads();

    // ---- Stage 4: horizontal 3-max ----
    for (int idx = t; idx < ER_H * TX; idx += NT) {
        int y = idx / TX;
        int x = idx % TX;
        s_m[y][x] = fmaxf(fmaxf(s_e[y][x], s_e[y][x + 1]), s_e[y][x + 2]);
    }
    __syncthreads();

    // ---- Stage 5: vertical 3-max + vectorized store ----
    // TY*TX/4 = 512 float4 stores
    for (int idx = t; idx < TY * (TX / 4); idx += NT) {
        int ty = idx / (TX / 4);
        int x4 = (idx % (TX / 4)) * 4;
        float4 v;
        v.x = fmaxf(fmaxf(s_m[ty][x4 + 0], s_m[ty + 1][x4 + 0]), s_m[ty + 2][x4 + 0]);
        v.y = fmaxf(fmaxf(s_m[ty][x4 + 1], s_m[ty + 1][x4 + 1]), s_m[ty + 2][x4 + 1]);
        v.z = fmaxf(fmaxf(s_m[ty][x4 + 2], s_m[ty + 1][x4 + 2]), s_m[ty + 2][x4 + 2]);
        v.w = fmaxf(fmaxf(s_m[ty][x4 + 3], s_m[ty + 1][x4 + 3]), s_m[ty + 2][x4 + 3]);
        *(float4*)(outp + (oy + ty) * IMG_W + ox + x4) = v;
    }
}

extern "C" void kernel_launch(void* const* d_in, const int* in_sizes, int n_in,
                              void* d_out, int out_size, void* d_ws, size_t ws_size,
                              hipStream_t stream) {
    const float* x = (const float*)d_in[0];
    float* out = (float*)d_out;
    // 16 batch * 3 channels = 48 independent 1024x1024 images
    dim3 grid(IMG_W / TX, IMG_H / TY, 48);
    dim3 block(NT);
    open3x3_fused<<<grid, block, 0, stream>>>(x, out);
}

// Round 2
// 353.283 us; speedup vs baseline: 1.0788x; 1.0788x over previous
//
#include <hip/hip_runtime.h>

// Morphological opening: dilate3x3(erode3x3(x)), flat SE, SAME padding.
// Register-only rolling-window kernel: no LDS, no barriers.
// Thread t owns output cols c0=4t..c0+3; block of 256 threads spans the full
// 1024-col width; each block walks ROWS output rows. Separable min/max in
// registers with a 1-deep software pipeline on the row loads.
//
// Semantics: erosion pads OOB *inputs* with +inf (identity for min);
// dilation sees erosion values only at valid positions — OOB erosion
// *positions* enter the max as -inf.

#define W 1024
#define H 1024
#define ROWS 32
#define NT 256

__global__ __launch_bounds__(NT)
void open3x3_reg(const float* __restrict__ in, float* __restrict__ out) {
    const int t  = threadIdx.x;
    const int c0 = 4 * t;                 // first output col of this thread
    const int y0 = blockIdx.y * ROWS;     // first output row of this block
    const size_t imgoff = (size_t)blockIdx.z * (size_t)(W * H);
    const float* img  = in  + imgoff;
    float*       outp = out + imgoff;

    const float PINF = __builtin_inff();
    const float NINF = -__builtin_inff();

    const bool has_l = (t > 0);    // cols c0-2,c0-1 in-bounds; position c0-1 valid
    const bool has_r = (t < NT-1); // cols c0+4,c0+5 in-bounds; position c0+4 valid

    // load input row r, cols c0-2..c0+5 -> x[0..7]; OOB -> +inf
    auto load_row = [&](int r, float x[8]) {
        if (r >= 0 && r < H) {               // uniform branch (r is block-uniform)
            const float* p = img + r * W;
            float4 m = *(const float4*)(p + c0);
            x[2] = m.x; x[3] = m.y; x[4] = m.z; x[5] = m.w;
            x[0] = has_l ? p[c0 - 2] : PINF;
            x[1] = has_l ? p[c0 - 1] : PINF;
            x[6] = has_r ? p[c0 + 4] : PINF;
            x[7] = has_r ? p[c0 + 5] : PINF;
        } else {
            #pragma unroll
            for (int i = 0; i < 8; i++) x[i] = PINF;
        }
    };
    // horizontal 3-min: hm[i] = min of input cols (c0-1+i)-1 .. (c0-1+i)+1
    auto hmin6 = [&](const float x[8], float hm[6]) {
        #pragma unroll
        for (int i = 0; i < 6; i++) hm[i] = fminf(fminf(x[i], x[i+1]), x[i+2]);
    };
    // erosion row r at positions c0-1..c0+4 from hmin rows r-1,r,r+1;
    // OOB positions (row or col) -> -inf
    auto erow = [&](int r, const float a[6], const float b[6], const float c[6],
                    float e[6]) {
        if (r >= 0 && r < H) {               // uniform branch
            #pragma unroll
            for (int i = 0; i < 6; i++) e[i] = fminf(fminf(a[i], b[i]), c[i]);
            if (!has_l) e[0] = NINF;         // position col -1
            if (!has_r) e[5] = NINF;         // position col 1024
        } else {
            #pragma unroll
            for (int i = 0; i < 6; i++) e[i] = NINF;
        }
    };
    // horizontal 3-max: hx[i] = max of erosion positions c0+i-1 .. c0+i+1
    auto hmax4 = [&](const float e[6], float hx[4]) {
        #pragma unroll
        for (int i = 0; i < 4; i++) hx[i] = fmaxf(fmaxf(e[i], e[i+1]), e[i+2]);
    };

    // ---- prologue ----
    float x[8];
    float hmP[6], hmQ[6], hmR[6], e[6];
    float hx0[4], hx1[4], hx2[4];

    load_row(y0 - 2, x); hmin6(x, hmP);
    load_row(y0 - 1, x); hmin6(x, hmQ);
    load_row(y0,     x); hmin6(x, hmR);
    erow(y0 - 1, hmP, hmQ, hmR, e); hmax4(e, hx0);

    // rotate: hmP=hmin(y0-1), hmQ=hmin(y0)
    #pragma unroll
    for (int i = 0; i < 6; i++) { hmP[i] = hmQ[i]; hmQ[i] = hmR[i]; }
    load_row(y0 + 1, x); hmin6(x, hmR);
    erow(y0, hmP, hmQ, hmR, e); hmax4(e, hx1);
    #pragma unroll
    for (int i = 0; i < 6; i++) { hmP[i] = hmQ[i]; hmQ[i] = hmR[i]; }
    // state now: hmP=hmin(y0), hmQ=hmin(y0+1); hx0=hmax(e(y0-1)), hx1=hmax(e(y0))

    float xc[8];                 // raw input row y+2 (pipelined)
    load_row(y0 + 2, xc);

    // ---- main loop over output rows ----
    #pragma unroll 4
    for (int k = 0; k < ROWS; k++) {
        const int y = y0 + k;
        float xn[8];
        if (k + 1 < ROWS) load_row(y + 3, xn);   // prefetch next row (uniform branch)

        hmin6(xc, hmR);                          // hmin(y+2)
        erow(y + 1, hmP, hmQ, hmR, e);           // erosion row y+1
        hmax4(e, hx2);

        float4 o;
        o.x = fmaxf(fmaxf(hx0[0], hx1[0]), hx2[0]);
        o.y = fmaxf(fmaxf(hx0[1], hx1[1]), hx2[1]);
        o.z = fmaxf(fmaxf(hx0[2], hx1[2]), hx2[2]);
        o.w = fmaxf(fmaxf(hx0[3], hx1[3]), hx2[3]);
        *(float4*)(outp + (size_t)y * W + c0) = o;

        // rotate pipeline state
        #pragma unroll
        for (int i = 0; i < 4; i++) { hx0[i] = hx1[i]; hx1[i] = hx2[i]; }
        #pragma unroll
        for (int i = 0; i < 6; i++) { hmP[i] = hmQ[i]; hmQ[i] = hmR[i]; }
        #pragma unroll
        for (int i = 0; i < 8; i++) xc[i] = xn[i];
    }
}

extern "C" void kernel_launch(void* const* d_in, const int* in_sizes, int n_in,
                              void* d_out, int out_size, void* d_ws, size_t ws_size,
                              hipStream_t stream) {
    const float* x = (const float*)d_in[0];
    float* out = (float*)d_out;
    // 16 batch * 3 channels = 48 independent 1024x1024 images
    dim3 grid(1, H / ROWS, 48);
    dim3 block(NT);
    open3x3_reg<<<grid, block, 0, stream>>>(x, out);
}

// Round 4
// 343.410 us; speedup vs baseline: 1.1098x; 1.0287x over previous
//
#include <hip/hip_runtime.h>

// Morphological opening: dilate3x3(erode3x3(x)), flat SE, SAME padding.
// Register-only rolling-window, fully-unrolled row loop, depth-3 prefetch ring,
// halo via wave shuffles (only lanes 0/63 do a 2-float predicated edge load).
//
// Semantics: erosion pads OOB *inputs* with +inf (identity for min);
// erosion values at OOB *positions* enter the dilation max as -inf.

#define W 1024
#define H 1024
#define ROWS 16
#define NT 256

typedef float nvec4 __attribute__((ext_vector_type(4)));  // native vector for nontemporal store

struct Row { float4 m; float eA, eB; };

__global__ __launch_bounds__(NT)
void open3x3_v3(const float* __restrict__ in, float* __restrict__ out) {
    const int t    = threadIdx.x;
    const int lane = t & 63;
    const int c0   = 4 * t;                   // wave w owns cols [256w, 256w+256)
    const int y0   = blockIdx.x * ROWS;
    const size_t imgoff = (size_t)blockIdx.y * (size_t)(W * H);
    const float* img  = in  + imgoff;
    float*       outp = out + imgoff;

    const float PINF = __builtin_inff();
    const float NINF = -__builtin_inff();
    const bool is_l  = (lane == 0);
    const bool is_r  = (lane == 63);
    const bool has_l = (c0 > 0);              // position c0-1 valid, cols c0-2.. exist
    const bool has_r = (c0 + 4 < W);          // position c0+4 valid, cols c0+4.. exist

    // Load raw input row r: float4 at c0 (+2 edge floats in lanes 0/63). OOB row -> +inf.
    auto load_row = [&](int r) -> Row {
        Row R;
        if (r >= 0 && r < H) {                // block-uniform branch
            const float* p = img + r * W;
            R.m = *(const float4*)(p + c0);
            float a = PINF, b = PINF;
            if ((is_l && has_l) || (is_r && has_r)) {   // 2 lanes per wave
                int ec = is_l ? (c0 - 2) : (c0 + 4);
                a = p[ec]; b = p[ec + 1];
            }
            R.eA = a; R.eB = b;
        } else {
            R.m = make_float4(PINF, PINF, PINF, PINF);
            R.eA = PINF; R.eB = PINF;
        }
        return R;
    };

    // Horizontal 3-min over the 8-col window c0-2..c0+5 -> hm[0..5] at positions c0-1..c0+4.
    auto hmin6 = [&](const Row& R, float hm[6]) {
        float x0 = __shfl_up(R.m.z, 1);       // col c0-2 (from left lane)
        float x1 = __shfl_up(R.m.w, 1);       // col c0-1
        float x6 = __shfl_down(R.m.x, 1);     // col c0+4 (from right lane)
        float x7 = __shfl_down(R.m.y, 1);     // col c0+5
        x0 = is_l ? R.eA : x0;
        x1 = is_l ? R.eB : x1;
        x6 = is_r ? R.eA : x6;
        x7 = is_r ? R.eB : x7;
        const float x2 = R.m.x, x3 = R.m.y, x4 = R.m.z, x5 = R.m.w;
        hm[0] = fminf(fminf(x0, x1), x2);
        hm[1] = fminf(fminf(x1, x2), x3);
        hm[2] = fminf(fminf(x2, x3), x4);
        hm[3] = fminf(fminf(x3, x4), x5);
        hm[4] = fminf(fminf(x4, x5), x6);
        hm[5] = fminf(fminf(x5, x6), x7);
    };

    // Erosion row r at positions c0-1..c0+4; OOB row/col positions -> -inf.
    auto erow = [&](int r, const float a[6], const float b[6], const float c[6], float e[6]) {
        if (r >= 0 && r < H) {                // block-uniform branch
            #pragma unroll
            for (int i = 0; i < 6; i++) e[i] = fminf(fminf(a[i], b[i]), c[i]);
            if (!has_l) e[0] = NINF;
            if (!has_r) e[5] = NINF;
        } else {
            #pragma unroll
            for (int i = 0; i < 6; i++) e[i] = NINF;
        }
    };

    auto hmax4 = [&](const float e[6], float hx[4]) {
        #pragma unroll
        for (int i = 0; i < 4; i++) hx[i] = fmaxf(fmaxf(e[i], e[i + 1]), e[i + 2]);
    };

    // ---- prologue: issue 7 independent loads up front ----
    Row r0 = load_row(y0 - 2);
    Row r1 = load_row(y0 - 1);
    Row r2 = load_row(y0);
    Row r3 = load_row(y0 + 1);
    Row buf[3];
    buf[0] = load_row(y0 + 2);
    buf[1] = load_row(y0 + 3);
    buf[2] = load_row(y0 + 4);

    float hmA[6], hmB[6], hmC[6], hmD[6];
    hmin6(r0, hmA); hmin6(r1, hmB); hmin6(r2, hmC); hmin6(r3, hmD);
    float e[6], hx0[4], hx1[4], hx2[4];
    erow(y0 - 1, hmA, hmB, hmC, e); hmax4(e, hx0);
    erow(y0,     hmB, hmC, hmD, e); hmax4(e, hx1);
    float hmP[6], hmQ[6], hmR[6];
    #pragma unroll
    for (int i = 0; i < 6; i++) { hmP[i] = hmC[i]; hmQ[i] = hmD[i]; }

    // ---- fully-unrolled main loop: compute output row y, prefetch raw row y+5 ----
    #pragma unroll
    for (int k = 0; k < ROWS; k++) {
        const int y = y0 + k;
        Row cur = buf[k % 3];                 // raw(y+2), loaded 3 iterations ago
        if (k < ROWS - 3) buf[k % 3] = load_row(y + 5);

        hmin6(cur, hmR);                      // hmin(y+2)
        erow(y + 1, hmP, hmQ, hmR, e);        // erosion row y+1
        hmax4(e, hx2);

        nvec4 o;
        o.x = fmaxf(fmaxf(hx0[0], hx1[0]), hx2[0]);
        o.y = fmaxf(fmaxf(hx0[1], hx1[1]), hx2[1]);
        o.z = fmaxf(fmaxf(hx0[2], hx1[2]), hx2[2]);
        o.w = fmaxf(fmaxf(hx0[3], hx1[3]), hx2[3]);
        __builtin_nontemporal_store(o, (nvec4*)(outp + (size_t)y * W + c0));

        #pragma unroll
        for (int i = 0; i < 4; i++) { hx0[i] = hx1[i]; hx1[i] = hx2[i]; }
        #pragma unroll
        for (int i = 0; i < 6; i++) { hmP[i] = hmQ[i]; hmQ[i] = hmR[i]; }
    }
}

extern "C" void kernel_launch(void* const* d_in, const int* in_sizes, int n_in,
                              void* d_out, int out_size, void* d_ws, size_t ws_size,
                              hipStream_t stream) {
    const float* x = (const float*)d_in[0];
    float* out = (float*)d_out;
    // 16 batch * 3 channels = 48 images; 64 row-tiles per image -> 3072 blocks
    dim3 grid(H / ROWS, 48);
    dim3 block(NT);
    open3x3_v3<<<grid, block, 0, stream>>>(x, out);
}